// Round 14
// baseline (286.094 us; speedup 1.0000x reference)
//
#include <hip/hip_runtime.h>
#include <hip/hip_bf16.h>
#include <stdint.h>

#define USER_DIM 3706
#define ITEM_DIM 6040
#define LATENT   512
#define BATCH    8192
#define XCOLS    (USER_DIM + ITEM_DIM)   // 9746
#define KPAD_U   3712                     // 116*32: two halves of 58 steps
#define KPAD_I   6144                     // 192*32: two halves of 96 steps

typedef float f32x4 __attribute__((ext_vector_type(4)));
typedef short bf16x8 __attribute__((ext_vector_type(8)));

#define VMCNT(n) asm volatile("s_waitcnt vmcnt(" #n ")" ::: "memory")
#define LGKM0    asm volatile("s_waitcnt lgkmcnt(0)" ::: "memory")

static __device__ __forceinline__ unsigned short f2bf(float f) {
    union { float f; unsigned int u; } v; v.f = f;
    unsigned int u = v.u;
    u += 0x7fffu + ((u >> 16) & 1u);   // RNE (finite inputs)
    return (unsigned short)(u >> 16);
}
static __device__ __forceinline__ float bf2f(unsigned int b) {
    union { unsigned int u; float f; } v; v.u = b << 16; return v.f;
}
static __device__ __forceinline__ unsigned short cvt1(float f) {
    union { __hip_bfloat16 h; unsigned short u; } cv;
    cv.h = __float2bfloat16(f);        // RNE; compiler pairs into v_cvt_pk_bf16_f32
    return cv.u;
}
static __device__ __forceinline__ void gload16(const void* g, void* l) {
    __builtin_amdgcn_global_load_lds(
        (const __attribute__((address_space(1))) void*)g,
        (__attribute__((address_space(3))) void*)l, 16, 0, 0);
}
static __device__ __forceinline__ void BARRIER() {
    __builtin_amdgcn_sched_barrier(0);
    __builtin_amdgcn_s_barrier();
    __builtin_amdgcn_sched_barrier(0);
}

// ---- Kernel 1: weight fp32 -> bf16, zero-padded K ----
__global__ void convert_w(const float* __restrict__ W, unsigned short* __restrict__ Wb,
                          int K, int Kpad) {
    int c = blockIdx.x * blockDim.x + threadIdx.x;
    int r = blockIdx.y;
    if (c >= Kpad) return;
    unsigned short o = 0;
    if (c < K) o = f2bf(W[(size_t)r * K + c]);
    Wb[(size_t)r * Kpad + c] = o;
}

// ---- Kernel 2: r6 body at 4 blocks/CU. 128x128 tile, BK=32, 4 waves, 32 KB LDS.
// A reg-staged single set (write-then-reload), write-side cvt_pk. B global_load_lds.
// Counted vmcnt mid-loop (never 0). 1024 blocks: every consecutive 4-group =
// {user kh0, user kh1, item kh0, item kh1} of one (mb,nb) -> 308 steps per CU.
// ALL outputs raw bf16 partials; bias+relu fused into rowdot.
__global__ __launch_bounds__(256, 4) void gemm_fused(
    const float* __restrict__ X,
    const unsigned short* __restrict__ WuB,
    const unsigned short* __restrict__ WiB,
    unsigned short* __restrict__ U0, unsigned short* __restrict__ U1,
    unsigned short* __restrict__ P0, unsigned short* __restrict__ P1)
{
    __shared__ unsigned short sA2[2][64 * 64];   // 2 x 8 KB bf16
    __shared__ unsigned short sB2[2][64 * 64];   // 2 x 8 KB bf16

    const int tid  = threadIdx.x;
    const int lane = tid & 63;
    const int wid  = tid >> 6;
    const int wm   = wid >> 1;
    const int wn   = wid & 1;

    // XCD-chunked bijective swizzle over 1024 blocks (= 8 * 128).
    const int bid = blockIdx.x;
    const int swz = (bid & 7) * 128 + (bid >> 3);
    const int r2  = swz & 3;           // 0,1 = user ; 2,3 = item
    const int q   = (swz >> 2) * 2 + (r2 & 1);   // 0..511 per tower
    const int mb  = q >> 3;            // 0..63
    const int nb  = (q >> 1) & 3;      // 0..3
    const int kh  = q & 1;             // K half

    int k0s, nt, xoff, Kpad;
    const unsigned short* WB;
    unsigned short* dst;
    if (r2 < 2) { k0s = kh * 58; nt = 58; xoff = 0;        Kpad = KPAD_U; WB = WuB;
                  dst = kh ? U1 : U0; }
    else        { k0s = kh * 96; nt = 96; xoff = USER_DIM; Kpad = KPAD_I; WB = WiB;
                  dst = kh ? P1 : P0; }

    // ---- staging lane geometry (LDS[seg][c8] holds global
    //      (row = seg*2 + ((c8^(seg&7))>>2), kchunk = (c8^(seg&7))&3)) ----
    const int l8  = lane >> 3;                 // seg within group
    const int c8w = lane & 7;                  // LDS chunk this lane fills
    const int s8  = c8w ^ l8;                  // source-side swizzled chunk
    const int spr = s8 >> 2;                   // source row parity
    const int skc = (s8 & 3) * 8;              // source k-col (elements)

    const int asg0 = wid * 16 + l8;            // A op0 seg
    const float* aptr0 = X + (size_t)(mb * 128 + asg0 * 2 + spr) * XCOLS + xoff;
    const float* aptr1 = aptr0 + (size_t)16 * XCOLS;   // op1 seg = asg0 + 8

    float4 Sa[2], Sb[2];                       // single A reg set (static idx)

    auto ALOAD = [&](int tk) {
        int kc = tk * 32 + skc;
        if (xoff + kc + 8 > XCOLS) kc = XCOLS - xoff - 8;  // tail: junk x 0-B
        Sa[0] = *(const float4*)(aptr0 + kc);
        Sa[1] = *(const float4*)(aptr0 + kc + 4);
        Sb[0] = *(const float4*)(aptr1 + kc);
        Sb[1] = *(const float4*)(aptr1 + kc + 4);
    };
    auto AWRITE = [&](int buf) {               // consumes Sa/Sb (auto vm-wait)
        unsigned short* sA = sA2[buf];
        uint4 w0, w1;
        w0.x = (unsigned)cvt1(Sa[0].x) | ((unsigned)cvt1(Sa[0].y) << 16);
        w0.y = (unsigned)cvt1(Sa[0].z) | ((unsigned)cvt1(Sa[0].w) << 16);
        w0.z = (unsigned)cvt1(Sa[1].x) | ((unsigned)cvt1(Sa[1].y) << 16);
        w0.w = (unsigned)cvt1(Sa[1].z) | ((unsigned)cvt1(Sa[1].w) << 16);
        w1.x = (unsigned)cvt1(Sb[0].x) | ((unsigned)cvt1(Sb[0].y) << 16);
        w1.y = (unsigned)cvt1(Sb[0].z) | ((unsigned)cvt1(Sb[0].w) << 16);
        w1.z = (unsigned)cvt1(Sb[1].x) | ((unsigned)cvt1(Sb[1].y) << 16);
        w1.w = (unsigned)cvt1(Sb[1].z) | ((unsigned)cvt1(Sb[1].w) << 16);
        *(uint4*)(sA + asg0 * 64 + c8w * 8) = w0;
        *(uint4*)(sA + (asg0 + 8) * 64 + c8w * 8) = w1;
    };
    auto ISSUE_B = [&](int tk, int buf) {
        const int kb = tk * 32;
        unsigned short* sB = sB2[buf];
        #pragma unroll
        for (int j = 0; j < 2; ++j) {
            const int i  = wid * 2 + j;                // 0..7
            const int rt = (i * 8 + l8) * 2 + spr;     // tile row
            const unsigned short* s =
                WB + (size_t)(nb * 128 + rt) * Kpad + kb + skc;
            gload16(s, sB + i * 512);                  // linear 1KB dest
        }
    };

    // ---- fragment read geometry (0-conflict) ----
    const int fr  = lane & 15;
    const int g   = lane >> 4;
    const int lro = (fr >> 1) * 64 + ((((fr & 1) * 4) + g) ^ (fr >> 1)) * 8;
    const int aro = wm * 2048 + lro;           // + mi*512
    const int bro = wn * 2048 + lro;           // + ni*512

    f32x4 acc[4][4];
    #pragma unroll
    for (int i = 0; i < 4; ++i)
        #pragma unroll
        for (int j = 0; j < 4; ++j) acc[i][j] = (f32x4)0.0f;

    auto COMPUTE = [&](int buf) {
        const unsigned short* sA = sA2[buf];
        const unsigned short* sB = sB2[buf];
        bf16x8 af[4], bfr[4];
        #pragma unroll
        for (int mi = 0; mi < 4; ++mi)
            af[mi] = *(const bf16x8*)(sA + aro + mi * 512);
        #pragma unroll
        for (int ni = 0; ni < 4; ++ni)
            bfr[ni] = *(const bf16x8*)(sB + bro + ni * 512);
        __builtin_amdgcn_s_setprio(1);
        #pragma unroll
        for (int mi = 0; mi < 4; ++mi)
            #pragma unroll
            for (int ni = 0; ni < 4; ++ni)
                acc[mi][ni] = __builtin_amdgcn_mfma_f32_16x16x32_bf16(
                    af[mi], bfr[ni], acc[mi][ni], 0, 0, 0);
        __builtin_amdgcn_s_setprio(0);
    };

    // ---- pipeline (r6 verbatim): 2 barriers/step, counted waits ----
    ALOAD(k0s);                     // A(0)             [4 vm]
    ISSUE_B(k0s, 0);                // B(0) -> lds0     [2 vm]
    AWRITE(0);                      // waits A(0) (auto vmcnt(2))
    ALOAD(k0s + 1);                 // A(1)
    LGKM0;
    VMCNT(4);                       // B(0) landed (A(1) stays in flight)
    BARRIER();                      // tile 0 ready
    ISSUE_B(k0s + 1, 1);            // B(1) in flight

    #pragma unroll 2
    for (int t = 0; t < nt - 2; ++t) {
        const int cur = t & 1;
        COMPUTE(cur);               // tile t
        AWRITE(cur ^ 1);            // A(t+1): regs (1 iter old) -> nxt
        ALOAD(k0s + t + 2);         // A(t+2) -> regs
        LGKM0;
        BARRIER();                  // cur reads done everywhere
        ISSUE_B(k0s + t + 2, cur);  // B(t+2) -> cur
        VMCNT(6);                   // retires B(t+1); A(t+2)+B(t+2) in flight
        BARRIER();                  // publish tile t+1
    }
    // t = nt-2 (cur = 0 since nt even)
    COMPUTE(0);
    AWRITE(1);                      // A(nt-1)
    LGKM0;
    BARRIER();
    VMCNT(0);                       // drain B(nt-1)
    BARRIER();
    COMPUTE(1);                     // tile nt-1

    // ---- epilogue: raw partial store (bias+relu in rowdot) ----
    const int cb = nb * 128 + wn * 64;
    const int rb = mb * 128 + wm * 64 + (lane >> 4) * 4;
    #pragma unroll
    for (int ni = 0; ni < 4; ++ni) {
        const int col = cb + ni * 16 + fr;
        #pragma unroll
        for (int mi = 0; mi < 4; ++mi) {
            f32x4 v = acc[mi][ni];
            #pragma unroll
            for (int r = 0; r < 4; ++r) {
                const int row = rb + mi * 16 + r;
                dst[(size_t)row * LATENT + col] = f2bf(v[r]);
            }
        }
    }
}

// ---- Kernel 3: out[b] = relu(U0+U1+bu) . relu(P0+P1+bi) ----
__global__ void rowdot(const unsigned short* __restrict__ U0,
                       const unsigned short* __restrict__ U1,
                       const unsigned short* __restrict__ P0,
                       const unsigned short* __restrict__ P1,
                       const float* __restrict__ bu,
                       const float* __restrict__ bi,
                       float* __restrict__ out) {
    const int lane = threadIdx.x & 63;
    const int w    = threadIdx.x >> 6;
    const int row  = blockIdx.x * 4 + w;
    const size_t base = (size_t)row * LATENT + lane * 8;
    const uint4 u0 = *(const uint4*)(U0 + base);
    const uint4 u1 = *(const uint4*)(U1 + base);
    const uint4 p0 = *(const uint4*)(P0 + base);
    const uint4 p1 = *(const uint4*)(P1 + base);
    const float4 bu0 = *(const float4*)(bu + lane * 8);
    const float4 bu1 = *(const float4*)(bu + lane * 8 + 4);
    const float4 bi0 = *(const float4*)(bi + lane * 8);
    const float4 bi1 = *(const float4*)(bi + lane * 8 + 4);
    const float bbu[8] = {bu0.x, bu0.y, bu0.z, bu0.w, bu1.x, bu1.y, bu1.z, bu1.w};
    const float bbi[8] = {bi0.x, bi0.y, bi0.z, bi0.w, bi1.x, bi1.y, bi1.z, bi1.w};
    const unsigned int* a0 = (const unsigned int*)&u0;
    const unsigned int* a1 = (const unsigned int*)&u1;
    const unsigned int* q0 = (const unsigned int*)&p0;
    const unsigned int* q1 = (const unsigned int*)&p1;
    float acc = 0.0f;
    #pragma unroll
    for (int q = 0; q < 4; ++q) {
        float ulo = fmaxf(bf2f(a0[q] & 0xffffu) + bf2f(a1[q] & 0xffffu) + bbu[2 * q], 0.0f);
        float uhi = fmaxf(bf2f(a0[q] >> 16)     + bf2f(a1[q] >> 16)     + bbu[2 * q + 1], 0.0f);
        float ilo = fmaxf(bf2f(q0[q] & 0xffffu) + bf2f(q1[q] & 0xffffu) + bbi[2 * q], 0.0f);
        float ihi = fmaxf(bf2f(q0[q] >> 16)     + bf2f(q1[q] >> 16)     + bbi[2 * q + 1], 0.0f);
        acc += ulo * ilo + uhi * ihi;
    }
    #pragma unroll
    for (int off = 32; off >= 1; off >>= 1)
        acc += __shfl_xor(acc, off, 64);
    if (lane == 0) out[row] = acc;
}

extern "C" void kernel_launch(void* const* d_in, const int* in_sizes, int n_in,
                              void* d_out, int out_size, void* d_ws, size_t ws_size,
                              hipStream_t stream) {
    const float* x  = (const float*)d_in[0];
    const float* Wu = (const float*)d_in[1];
    const float* bu = (const float*)d_in[2];
    const float* Wi = (const float*)d_in[3];
    const float* bi = (const float*)d_in[4];
    float* out = (float*)d_out;

    unsigned short* WuB = (unsigned short*)d_ws;                  // 512*3712 bf16
    unsigned short* WiB = WuB + (size_t)LATENT * KPAD_U;          // 512*6144 bf16
    unsigned short* U0  = WiB + (size_t)LATENT * KPAD_I;          // 8 MB
    unsigned short* U1  = U0  + (size_t)BATCH * LATENT;           // 8 MB
    unsigned short* P0  = U1  + (size_t)BATCH * LATENT;           // 8 MB
    unsigned short* P1  = P0  + (size_t)BATCH * LATENT;           // 8 MB

    convert_w<<<dim3((KPAD_U + 255) / 256, LATENT), 256, 0, stream>>>(Wu, WuB, USER_DIM, KPAD_U);
    convert_w<<<dim3((KPAD_I + 255) / 256, LATENT), 256, 0, stream>>>(Wi, WiB, ITEM_DIM, KPAD_I);

    // 1024 blocks = 4 per CU co-resident; {u-kh0, u-kh1, i-kh0, i-kh1} per group.
    gemm_fused<<<1024, 256, 0, stream>>>(x, WuB, WiB, U0, U1, P0, P1);

    rowdot<<<BATCH / 4, 256, 0, stream>>>(U0, U1, P0, P1, bu, bi, out);
}